// Round 15
// baseline (896.567 us; speedup 1.0000x reference)
//
#include <hip/hip_runtime.h>
#include <stdint.h>

#define PP 920
#define FF 5
#define BBATCH 4
#define CC 256
#define NN 4600          // FF*PP
#define HH 8
#define MROWS 18400      // BBATCH*NN
#define M2ROWS 92000     // BBATCH*NN*FF
#define SCALE 0.17677669529663687f

// EVIDENCE LOG:
//  - Inputs f32 bound BY SIZE; outputs f32: out=d_out[0:4710400), attn=[4710400:5446400).
//  - R12 (16x16 MFMA, K/V LDS-staged): 328us total, flash 208us, LDS-read-bound
//    (~500 LDS cyc vs 256 MFMA cyc per chunk-wave), conflicts 2.47e7 (unpadded Ps).
//  - R13: VGPR cap 128 via launch_bounds -> spill -> 457us. Lesson: never cap below acc set.
//  - R14: L1-direct fragments -> uncoalesced 64-line gathers per load -> 500us, both pipes
//    idle. Lesson: LDS staging exists to convert coalesced global into random LDS access.
//  - R15: mfma 32x32x16 (2x arithmetic intensity per LDS byte, wave covers 32 q-rows),
//    per-wave private Ps (no P barrier, validated R14), 40-short strides (4-way worst),
//    NO launch_bounds cap.

typedef short bf16x8 __attribute__((ext_vector_type(8)));
typedef float f32x4 __attribute__((ext_vector_type(4)));
typedef float f32x16 __attribute__((ext_vector_type(16)));
typedef uint32_t u32;

#define MFMA16 __builtin_amdgcn_mfma_f32_16x16x32_bf16
#define MFMA32 __builtin_amdgcn_mfma_f32_32x32x16_bf16

__device__ __forceinline__ float b2f(unsigned short s){
  u32 u = ((u32)s) << 16; float f; __builtin_memcpy(&f, &u, 4); return f;
}
__device__ __forceinline__ unsigned short f2b(float f){
  u32 u; __builtin_memcpy(&u, &f, 4);
  u = (u + 0x7FFFu + ((u >> 16) & 1u)) >> 16;   // round-to-nearest-even
  return (unsigned short)u;
}

// ---------------- prep ----------------

__global__ void k15_cast(const float* __restrict__ in, short* __restrict__ out, int n){
  int i = blockIdx.x*256 + threadIdx.x;
  if (i < n) out[i] = (short)f2b(in[i]);
}

__global__ void k15_make_xb(const float* __restrict__ x, short* __restrict__ xb){
  int i = blockIdx.x*256 + threadIdx.x;       // one thread per 4 elems
  long e0 = (long)i*4;
  if (e0 >= (long)MROWS*CC) return;
  int row = (int)(e0 >> 8); int c = (int)(e0 & 255);
  int b = row / NN; int s = row - b*NN; int f = s / PP; int p = s - f*PP;
  const float4 v = *(const float4*)(x + ((size_t)(p*(BBATCH*FF) + b*FF + f))*CC + c);
  unsigned short o[4];
  o[0]=f2b(v.x); o[1]=f2b(v.y); o[2]=f2b(v.z); o[3]=f2b(v.w);
  *(ushort4*)(xb + e0) = *(ushort4*)o;
}

__global__ void k15_zero(short* p, int n){
  int i = blockIdx.x*256 + threadIdx.x;
  if (i < n) p[i] = 0;
}

// ---------------- MFMA GEMM (unchanged — passed R12-R14) ----------------
template<int MODE>
__launch_bounds__(256)
__global__ void k15_gemm(const short* __restrict__ A, const short* __restrict__ Bw,
                         short* __restrict__ Cout, float* __restrict__ FCout,
                         const float* __restrict__ bias,
                         int M, int lda, int ldc, float alpha)
{
  __shared__ short As[128][40];
  __shared__ short Bs[128][40];
  const int tid = threadIdx.x;
  const int m0 = blockIdx.x*128, n0 = blockIdx.y*128;
  const int w = tid >> 6, l = tid & 63;
  const int wm = (w >> 1)*64, wn = (w & 1)*64;
  const int lr = l & 15, lg = l >> 4;

  f32x4 acc[4][4] = {};

  for (int k0 = 0; k0 < 256; k0 += 32){
    #pragma unroll
    for (int i = 0; i < 2; i++){
      int v = tid + 256*i;               // 0..511
      int ar = v >> 2, as = (v & 3)*8;
      int grow = m0 + ar; if (grow >= M) grow = M - 1;
      *(uint4*)(&As[ar][as]) = *(const uint4*)(A + (size_t)grow*lda + k0 + as);
      *(uint4*)(&Bs[ar][as]) = *(const uint4*)(Bw + (size_t)(n0 + ar)*256 + k0 + as);
    }
    __syncthreads();
    bf16x8 af[4], bfr[4];
    #pragma unroll
    for (int i = 0; i < 4; i++) af[i]  = *(const bf16x8*)(&As[wm + i*16 + lr][lg*8]);
    #pragma unroll
    for (int j = 0; j < 4; j++) bfr[j] = *(const bf16x8*)(&Bs[wn + j*16 + lr][lg*8]);
    #pragma unroll
    for (int i = 0; i < 4; i++)
      #pragma unroll
      for (int j = 0; j < 4; j++)
        acc[i][j] = MFMA16(af[i], bfr[j], acc[i][j], 0, 0, 0);
    __syncthreads();
  }

  #pragma unroll
  for (int i = 0; i < 4; i++){
    #pragma unroll
    for (int r = 0; r < 4; r++){
      int m = m0 + wm + i*16 + lg*4 + r;
      if (m >= M) continue;
      #pragma unroll
      for (int j = 0; j < 4; j++){
        int n = n0 + wn + j*16 + lr;
        float v = acc[i][j][r]*alpha;
        if (MODE == 1){
          v += bias[n];
          int b = m / NN, s = m - b*NN; int f = s / PP, p = s - f*PP;
          FCout[(size_t)(p*(BBATCH*FF) + b*FF + f)*CC + n] = v;    // f32 store
        } else {
          Cout[(size_t)m*ldc + n] = (short)f2b(v);
        }
      }
    }
  }
}

// ---------------- V transpose (unchanged) ----------------
__launch_bounds__(256)
__global__ void k15_vt(const short* __restrict__ qkv, short* __restrict__ vt){
  __shared__ short t[64][80];
  const int p0 = blockIdx.x*64;
  const int c0 = blockIdx.y*64;
  const int bf = blockIdx.z;
  const int b = bf / FF, f = bf - b*FF;
  const int tid = threadIdx.x;
  #pragma unroll
  for (int i = 0; i < 2; i++){
    int v = tid + 256*i;                 // 0..511
    int pr = v >> 3, sg = (v & 7)*8;
    uint4 val = make_uint4(0,0,0,0);
    int p = p0 + pr;
    if (p < PP)
      val = *(const uint4*)(qkv + ((size_t)(b*NN + f*PP + p))*768 + 512 + c0 + sg);
    *(uint4*)(&t[pr][sg]) = val;
  }
  __syncthreads();
  #pragma unroll
  for (int i = 0; i < 2; i++){
    int v = tid + 256*i;
    int cr = v & 63, pg = v >> 6;        // pg 0..7
    int pbase = p0 + pg*8;
    if (pbase < 928){
      unsigned short o[8];
      #pragma unroll
      for (int jj = 0; jj < 8; jj++) o[jj] = (unsigned short)t[pg*8 + jj][cr];
      *(uint4*)(vt + ((size_t)(bf*CC + c0 + cr))*928 + pbase) = *(uint4*)o;
    }
  }
}

// ---------------- Stage-1 flash v4: 32x32x16 MFMA, K/V LDS-staged, per-wave Ps ----------------
// grid (36, 5, 4). 4 waves; wave w owns q rows qt*128 + w*32 .. +31.
// A/B frag rule (mirrors verified 16x16): row/col = l&31, k = 8*(l>>5)+j.
// C/D (HW-verified m74/m101): col = l&31, row = (reg&3)+8*(reg>>2)+4*(l>>5).
__global__ void k15_flash(const short* __restrict__ qkv, const short* __restrict__ vt,
                          short* __restrict__ x1, short* __restrict__ xd)
{
  __shared__ short Ks[32][264];     // 32 keys x 256 c (+8 pad)
  __shared__ short Vs[256][40];     // 256 c x 32 keys (+8 pad)
  __shared__ short Ps[4][32][40];   // per-wave P tile (no cross-wave sharing)

  const int qt = blockIdx.x, f = blockIdx.y, b = blockIdx.z;
  const int tid = threadIdx.x, w = tid >> 6, l = tid & 63;
  const int cl = l & 31, hi = l >> 5;
  const int qbase = qt*128 + w*32;

  // Q A-fragments in registers for all 29 chunks (16 mfma K-steps x 8 bf16)
  bf16x8 qa[16];
  {
    int qrow = qbase + cl; if (qrow > NN - 1) qrow = NN - 1;
    const short* qp = qkv + (size_t)(b*NN + qrow)*768 + hi*8;
    #pragma unroll
    for (int kk = 0; kk < 16; kk++) qa[kk] = *(const bf16x8*)(qp + kk*16);
  }

  f32x16 o[8] = {};          // 32q x 256c accumulator (128 VGPR)
  float den[16] = {};        // per-lane partial softmax denominators

  const size_t krow0 = (size_t)(b*NN + f*PP)*768 + 256;
  const short* vtp = vt + (size_t)((b*FF + f)*CC)*928;

  for (int ch = 0; ch < 29; ch++){
    const int key0 = ch*32;
    // stage K chunk (32 keys x 256 c) — coalesced
    #pragma unroll
    for (int i = 0; i < 4; i++){
      int v = tid + 256*i;                   // 0..1023
      int kr = v >> 5, ks = (v & 31)*8;
      *(uint4*)(&Ks[kr][ks]) = *(const uint4*)(qkv + krow0 + (size_t)(key0 + kr)*768 + ks);
    }
    // stage V^T chunk (256 c x 32 keys) — one 64B line per thread
    {
      const short* vp = vtp + (size_t)tid*928 + key0;
      #pragma unroll
      for (int i = 0; i < 4; i++)
        *(uint4*)(&Vs[tid][i*8]) = *(const uint4*)(vp + i*8);
    }
    __syncthreads();

    // S = Q(32x256) @ K(32x256)^T : 16 x mfma_32x32x16
    f32x16 s = {};
    #pragma unroll
    for (int kk = 0; kk < 16; kk++){
      bf16x8 kb = *(const bf16x8*)(&Ks[cl][kk*16 + hi*8]);
      s = MFMA32(qa[kk], kb, s, 0, 0, 0);
    }

    // fixed-max softmax numerators (|logit| bounded ~1.7); lane's key = key0 + cl
    const bool valid = (key0 + cl) < PP;
    #pragma unroll
    for (int r = 0; r < 16; r++){
      float v = valid ? s[r]*SCALE : -1e30f;
      float p = __expf(v);
      den[r] += p;
      int qr = (r & 3) + 8*(r >> 2) + 4*hi;
      Ps[w][qr][cl] = (short)f2b(p);
    }
    // no barrier: wave w writes AND reads only Ps[w] (same-wave DS ops are in-order;
    // pattern validated on HW by R14's passing refcheck)

    // O += P(32x32) @ V: A-frags from Ps, B-frags from Vs (V^T rows)
    bf16x8 pa0 = *(const bf16x8*)(&Ps[w][cl][hi*8]);
    bf16x8 pa1 = *(const bf16x8*)(&Ps[w][cl][16 + hi*8]);
    #pragma unroll
    for (int ct = 0; ct < 8; ct++){
      bf16x8 vb0 = *(const bf16x8*)(&Vs[ct*32 + cl][hi*8]);
      bf16x8 vb1 = *(const bf16x8*)(&Vs[ct*32 + cl][16 + hi*8]);
      o[ct] = MFMA32(pa0, vb0, o[ct], 0, 0, 0);
      o[ct] = MFMA32(pa1, vb1, o[ct], 0, 0, 0);
    }
    __syncthreads();   // protect Ks/Vs before next staging
  }

  // epilogue: reduce den across the 32 key-lanes (offsets stay within each 32-half),
  // normalize, store
  #pragma unroll
  for (int r = 0; r < 16; r++){
    float dsum = den[r];
    #pragma unroll
    for (int off = 16; off >= 1; off >>= 1) dsum += __shfl_xor(dsum, off);
    float inv = 1.f/dsum;
    int srow = qbase + (r & 3) + 8*(r >> 2) + 4*hi;
    if (srow >= NN) continue;
    bool dg = (srow/PP == f);
    size_t x1base = ((size_t)(b*NN + srow)*FF + f)*CC;
    size_t xdbase = (size_t)(b*NN + srow)*CC;
    #pragma unroll
    for (int ct = 0; ct < 8; ct++){
      short val = (short)f2b(o[ct][r]*inv);
      x1[x1base + ct*32 + cl] = val;
      if (dg) xd[xdbase + ct*32 + cl] = val;
    }
  }
}

// ---------------- Stage-2 attention (unchanged — passed R12-R14) ----------------
__launch_bounds__(256)
__global__ void k15_attn2(const short* __restrict__ q2b, const short* __restrict__ k2v2,
                          float* __restrict__ attnp, short* __restrict__ x2)
{
  int idx = blockIdx.x*256 + threadIdx.x;
  if (idx >= MROWS*HH) return;
  const int h = idx & 7; const int row = idx >> 3;   // row = b*N + s

  float qv[32];
  {
    const short* qp = q2b + (size_t)row*CC + h*32;
    #pragma unroll
    for (int s4 = 0; s4 < 4; s4++){
      uint4 u = *(const uint4*)(qp + s4*8);
      const unsigned short* sp = (const unsigned short*)&u;
      #pragma unroll
      for (int j = 0; j < 8; j++) qv[s4*8 + j] = b2f(sp[j]);
    }
  }

  float lgt[FF];
  #pragma unroll
  for (int f = 0; f < FF; f++){
    const short* kp = k2v2 + ((size_t)row*FF + f)*512 + h*32;
    float a = 0.f;
    #pragma unroll
    for (int s4 = 0; s4 < 4; s4++){
      uint4 u = *(const uint4*)(kp + s4*8);
      const unsigned short* sp = (const unsigned short*)&u;
      #pragma unroll
      for (int j = 0; j < 8; j++) a += qv[s4*8 + j]*b2f(sp[j]);
    }
    lgt[f] = a;
  }

  float mx = lgt[0];
  #pragma unroll
  for (int f = 1; f < FF; f++) mx = fmaxf(mx, lgt[f]);
  float pr[FF], ps = 0.f;
  #pragma unroll
  for (int f = 0; f < FF; f++){ pr[f] = __expf(lgt[f] - mx); ps += pr[f]; }
  float inv = 1.f/ps;

  const int b = row / NN; const int s = row - b*NN;
  size_t ab = (((size_t)(b*HH + h))*NN + s)*FF;
  #pragma unroll
  for (int f = 0; f < FF; f++) attnp[ab + f] = pr[f]*inv;   // f32 store

  float xa[32] = {};
  #pragma unroll
  for (int f = 0; f < FF; f++){
    const short* vp = k2v2 + ((size_t)row*FF + f)*512 + 256 + h*32;
    float wgt = pr[f]*inv;
    #pragma unroll
    for (int s4 = 0; s4 < 4; s4++){
      uint4 u = *(const uint4*)(vp + s4*8);
      const unsigned short* sp = (const unsigned short*)&u;
      #pragma unroll
      for (int j = 0; j < 8; j++) xa[s4*8 + j] += wgt*b2f(sp[j]);
    }
  }
  #pragma unroll
  for (int s4 = 0; s4 < 4; s4++){
    unsigned short o[8];
    #pragma unroll
    for (int j = 0; j < 8; j++) o[j] = f2b(xa[s4*8 + j]);
    *(uint4*)(x2 + (size_t)row*CC + h*32 + s4*8) = *(uint4*)o;
  }
}

// ---------------- launcher ----------------
extern "C" void kernel_launch(void* const* d_in, const int* in_sizes, int n_in,
                              void* d_out, int out_size, void* d_ws, size_t ws_size,
                              hipStream_t stream)
{
  // bind inputs BY SIZE (validated rounds 10-14)
  int ix=-1, iwqkv=-1, iwpq=-1, iwpkv=-1, iwproj=-1, ib=-1;
  for (int i = 0; i < n_in; i++){
    switch (in_sizes[i]){
      case 4710400: ix = i; break;
      case 196608:  iwqkv = i; break;
      case 131072:  iwpkv = i; break;
      case 256:     ib = i; break;
      case 65536:   if (iwpq < 0) iwpq = i; else iwproj = i; break;
      default: break;
    }
  }
  if (ix < 0 || iwqkv < 0 || iwpq < 0 || iwpkv < 0 || iwproj < 0 || ib < 0){
    ix=0; iwqkv=1; iwpq=2; iwpkv=3; iwproj=4; ib=5;
  }
  const float* x     = (const float*)d_in[ix];
  const float* Wqkv  = (const float*)d_in[iwqkv];
  const float* Wpq   = (const float*)d_in[iwpq];
  const float* Wpkv  = (const float*)d_in[iwpkv];
  const float* Wproj = (const float*)d_in[iwproj];
  const float* bproj = (const float*)d_in[ib];

  char* ws = (char*)d_ws;
  if (ws_size < 208269312ULL) return;

  short* wq    = (short*)(ws + 0);               // 768*256
  short* wpq   = (short*)(ws + 393216);          // 256*256
  short* wpkv  = (short*)(ws + 524288);          // 512*256
  short* wprj  = (short*)(ws + 786432);          // 256*256
  short* xb    = (short*)(ws + 917504);          // 18400x256
  short* qkv   = (short*)(ws + 10338304);        // 18408x768 (8 slack rows zeroed)
  short* vt    = (short*)(ws + 38612992);        // 20x256x928
  short* x1    = (short*)(ws + 48115712);        // 92000x256
  short* xd    = (short*)(ws + 95219712);        // 18400x256
  short* k2v2  = (short*)(ws + 104640512);       // 92000x512
  short* q2b   = (short*)(ws + 198848512);       // 18400x256 -> end 208,269,312
  short* x2    = xb;                             // alias: xb dead after QKV GEMM

  float* outp  = (float*)d_out;                  // f32 out   [0 : 4,710,400)
  float* attnp = outp + 4710400;                 // f32 attn  [4,710,400 : 5,446,400)

  k15_cast<<<dim3(768), dim3(256), 0, stream>>>(Wqkv,  wq,   196608);
  k15_cast<<<dim3(256), dim3(256), 0, stream>>>(Wpq,   wpq,  65536);
  k15_cast<<<dim3(512), dim3(256), 0, stream>>>(Wpkv,  wpkv, 131072);
  k15_cast<<<dim3(256), dim3(256), 0, stream>>>(Wproj, wprj, 65536);
  k15_make_xb<<<dim3(4600), dim3(256), 0, stream>>>(x, xb);
  k15_zero<<<dim3(24), dim3(256), 0, stream>>>(qkv + (size_t)MROWS*768, 6144);

  // qkv = xb @ Wqkv^T           (MFMA)
  k15_gemm<0><<<dim3(144, 6), dim3(256), 0, stream>>>(xb, wq, qkv, nullptr, nullptr, MROWS, 256, 768, 1.0f);
  // V transpose for flash
  k15_vt<<<dim3(15, 4, 20), dim3(256), 0, stream>>>(qkv, vt);
  // stage-1 flash attention v4  (mfma 32x32x16)
  k15_flash<<<dim3(36, 5, 4), dim3(256), 0, stream>>>(qkv, vt, x1, xd);
  // kv2 = x1 @ Wpkv^T           (MFMA)
  k15_gemm<0><<<dim3(719, 4), dim3(256), 0, stream>>>(x1, wpkv, k2v2, nullptr, nullptr, M2ROWS, 256, 512, 1.0f);
  // q2 = xd @ Wpq^T * scale     (MFMA)
  k15_gemm<0><<<dim3(144, 2), dim3(256), 0, stream>>>(xd, wpq, q2b, nullptr, nullptr, MROWS, 256, 256, SCALE);
  // stage-2 attention (f32 attn, bf16 x2)
  k15_attn2<<<dim3(575), dim3(256), 0, stream>>>(q2b, k2v2, attnp, x2);
  // out = x2 @ Wproj^T + bias   (MFMA, f32 permuted store)
  k15_gemm<1><<<dim3(144, 2), dim3(256), 0, stream>>>(x2, wprj, nullptr, outp, bproj, MROWS, 256, 256, 1.0f);
}

// Round 16
// 353.946 us; speedup vs baseline: 2.5331x; 2.5331x over previous
//
#include <hip/hip_runtime.h>
#include <stdint.h>

#define PP 920
#define FF 5
#define BBATCH 4
#define CC 256
#define NN 4600          // FF*PP
#define HH 8
#define MROWS 18400      // BBATCH*NN
#define M2ROWS 92000     // BBATCH*NN*FF
#define SCALE 0.17677669529663687f

// EVIDENCE LOG:
//  - Inputs f32 bound BY SIZE; outputs f32: out=d_out[0:4710400), attn=[4710400:5446400).
//  - R12 (16x16, K/V LDS): flash 208us, MfmaUtil 18%, conflicts 2.47e7.
//  - R13: launch_bounds(256,2) capped VGPR=128 < ~200 live -> spill -> 457us.
//  - R14: L1-direct fragments -> uncoalesced gathers -> 500us. Stage in LDS, always.
//  - R15 (32x32 MFMA, 40-short strides): PASS, absmax unchanged (32x32 frag layout
//    HW-VALIDATED), conflicts ZERO — but NO launch_bounds -> implicit 1024-thread
//    assumption -> VGPR capped 64 -> 240 regs spilled -> FETCH 1.6GB, flash 763us.
//  - R16: ONE change — __launch_bounds__(256) on flash (max-threads only, no min-waves).

typedef short bf16x8 __attribute__((ext_vector_type(8)));
typedef float f32x4 __attribute__((ext_vector_type(4)));
typedef float f32x16 __attribute__((ext_vector_type(16)));
typedef uint32_t u32;

#define MFMA16 __builtin_amdgcn_mfma_f32_16x16x32_bf16
#define MFMA32 __builtin_amdgcn_mfma_f32_32x32x16_bf16

__device__ __forceinline__ float b2f(unsigned short s){
  u32 u = ((u32)s) << 16; float f; __builtin_memcpy(&f, &u, 4); return f;
}
__device__ __forceinline__ unsigned short f2b(float f){
  u32 u; __builtin_memcpy(&u, &f, 4);
  u = (u + 0x7FFFu + ((u >> 16) & 1u)) >> 16;   // round-to-nearest-even
  return (unsigned short)u;
}

// ---------------- prep ----------------

__global__ void k16_cast(const float* __restrict__ in, short* __restrict__ out, int n){
  int i = blockIdx.x*256 + threadIdx.x;
  if (i < n) out[i] = (short)f2b(in[i]);
}

__global__ void k16_make_xb(const float* __restrict__ x, short* __restrict__ xb){
  int i = blockIdx.x*256 + threadIdx.x;       // one thread per 4 elems
  long e0 = (long)i*4;
  if (e0 >= (long)MROWS*CC) return;
  int row = (int)(e0 >> 8); int c = (int)(e0 & 255);
  int b = row / NN; int s = row - b*NN; int f = s / PP; int p = s - f*PP;
  const float4 v = *(const float4*)(x + ((size_t)(p*(BBATCH*FF) + b*FF + f))*CC + c);
  unsigned short o[4];
  o[0]=f2b(v.x); o[1]=f2b(v.y); o[2]=f2b(v.z); o[3]=f2b(v.w);
  *(ushort4*)(xb + e0) = *(ushort4*)o;
}

__global__ void k16_zero(short* p, int n){
  int i = blockIdx.x*256 + threadIdx.x;
  if (i < n) p[i] = 0;
}

// ---------------- MFMA GEMM (unchanged — passed R12-R15) ----------------
template<int MODE>
__launch_bounds__(256)
__global__ void k16_gemm(const short* __restrict__ A, const short* __restrict__ Bw,
                         short* __restrict__ Cout, float* __restrict__ FCout,
                         const float* __restrict__ bias,
                         int M, int lda, int ldc, float alpha)
{
  __shared__ short As[128][40];
  __shared__ short Bs[128][40];
  const int tid = threadIdx.x;
  const int m0 = blockIdx.x*128, n0 = blockIdx.y*128;
  const int w = tid >> 6, l = tid & 63;
  const int wm = (w >> 1)*64, wn = (w & 1)*64;
  const int lr = l & 15, lg = l >> 4;

  f32x4 acc[4][4] = {};

  for (int k0 = 0; k0 < 256; k0 += 32){
    #pragma unroll
    for (int i = 0; i < 2; i++){
      int v = tid + 256*i;               // 0..511
      int ar = v >> 2, as = (v & 3)*8;
      int grow = m0 + ar; if (grow >= M) grow = M - 1;
      *(uint4*)(&As[ar][as]) = *(const uint4*)(A + (size_t)grow*lda + k0 + as);
      *(uint4*)(&Bs[ar][as]) = *(const uint4*)(Bw + (size_t)(n0 + ar)*256 + k0 + as);
    }
    __syncthreads();
    bf16x8 af[4], bfr[4];
    #pragma unroll
    for (int i = 0; i < 4; i++) af[i]  = *(const bf16x8*)(&As[wm + i*16 + lr][lg*8]);
    #pragma unroll
    for (int j = 0; j < 4; j++) bfr[j] = *(const bf16x8*)(&Bs[wn + j*16 + lr][lg*8]);
    #pragma unroll
    for (int i = 0; i < 4; i++)
      #pragma unroll
      for (int j = 0; j < 4; j++)
        acc[i][j] = MFMA16(af[i], bfr[j], acc[i][j], 0, 0, 0);
    __syncthreads();
  }

  #pragma unroll
  for (int i = 0; i < 4; i++){
    #pragma unroll
    for (int r = 0; r < 4; r++){
      int m = m0 + wm + i*16 + lg*4 + r;
      if (m >= M) continue;
      #pragma unroll
      for (int j = 0; j < 4; j++){
        int n = n0 + wn + j*16 + lr;
        float v = acc[i][j][r]*alpha;
        if (MODE == 1){
          v += bias[n];
          int b = m / NN, s = m - b*NN; int f = s / PP, p = s - f*PP;
          FCout[(size_t)(p*(BBATCH*FF) + b*FF + f)*CC + n] = v;    // f32 store
        } else {
          Cout[(size_t)m*ldc + n] = (short)f2b(v);
        }
      }
    }
  }
}

// ---------------- V transpose (unchanged) ----------------
__launch_bounds__(256)
__global__ void k16_vt(const short* __restrict__ qkv, short* __restrict__ vt){
  __shared__ short t[64][80];
  const int p0 = blockIdx.x*64;
  const int c0 = blockIdx.y*64;
  const int bf = blockIdx.z;
  const int b = bf / FF, f = bf - b*FF;
  const int tid = threadIdx.x;
  #pragma unroll
  for (int i = 0; i < 2; i++){
    int v = tid + 256*i;                 // 0..511
    int pr = v >> 3, sg = (v & 7)*8;
    uint4 val = make_uint4(0,0,0,0);
    int p = p0 + pr;
    if (p < PP)
      val = *(const uint4*)(qkv + ((size_t)(b*NN + f*PP + p))*768 + 512 + c0 + sg);
    *(uint4*)(&t[pr][sg]) = val;
  }
  __syncthreads();
  #pragma unroll
  for (int i = 0; i < 2; i++){
    int v = tid + 256*i;
    int cr = v & 63, pg = v >> 6;        // pg 0..7
    int pbase = p0 + pg*8;
    if (pbase < 928){
      unsigned short o[8];
      #pragma unroll
      for (int jj = 0; jj < 8; jj++) o[jj] = (unsigned short)t[pg*8 + jj][cr];
      *(uint4*)(vt + ((size_t)(bf*CC + c0 + cr))*928 + pbase) = *(uint4*)o;
    }
  }
}

// ---------------- Stage-1 flash v5: 32x32x16 MFMA, K/V LDS-staged, per-wave Ps ----------------
// grid (36, 5, 4). 4 waves; wave w owns q rows qt*128 + w*32 .. +31.
// Layouts HW-validated by R15's passing refcheck (absmax == naive baseline).
__launch_bounds__(256)       // max-threads only: allows up to ~256 VGPR/wave, no spill
__global__ void k16_flash(const short* __restrict__ qkv, const short* __restrict__ vt,
                          short* __restrict__ x1, short* __restrict__ xd)
{
  __shared__ short Ks[32][264];     // 32 keys x 256 c (+8 pad)
  __shared__ short Vs[256][40];     // 256 c x 32 keys (+8 pad)
  __shared__ short Ps[4][32][40];   // per-wave P tile (no cross-wave sharing)

  const int qt = blockIdx.x, f = blockIdx.y, b = blockIdx.z;
  const int tid = threadIdx.x, w = tid >> 6, l = tid & 63;
  const int cl = l & 31, hi = l >> 5;
  const int qbase = qt*128 + w*32;

  // Q A-fragments in registers for all 29 chunks (16 mfma K-steps x 8 bf16)
  bf16x8 qa[16];
  {
    int qrow = qbase + cl; if (qrow > NN - 1) qrow = NN - 1;
    const short* qp = qkv + (size_t)(b*NN + qrow)*768 + hi*8;
    #pragma unroll
    for (int kk = 0; kk < 16; kk++) qa[kk] = *(const bf16x8*)(qp + kk*16);
  }

  f32x16 o[8] = {};          // 32q x 256c accumulator (128 VGPR)
  float den[16] = {};        // per-lane partial softmax denominators

  const size_t krow0 = (size_t)(b*NN + f*PP)*768 + 256;
  const short* vtp = vt + (size_t)((b*FF + f)*CC)*928;

  for (int ch = 0; ch < 29; ch++){
    const int key0 = ch*32;
    // stage K chunk (32 keys x 256 c) — coalesced
    #pragma unroll
    for (int i = 0; i < 4; i++){
      int v = tid + 256*i;                   // 0..1023
      int kr = v >> 5, ks = (v & 31)*8;
      *(uint4*)(&Ks[kr][ks]) = *(const uint4*)(qkv + krow0 + (size_t)(key0 + kr)*768 + ks);
    }
    // stage V^T chunk (256 c x 32 keys) — one 64B line per thread
    {
      const short* vp = vtp + (size_t)tid*928 + key0;
      #pragma unroll
      for (int i = 0; i < 4; i++)
        *(uint4*)(&Vs[tid][i*8]) = *(const uint4*)(vp + i*8);
    }
    __syncthreads();

    // S = Q(32x256) @ K(32x256)^T : 16 x mfma_32x32x16
    f32x16 s = {};
    #pragma unroll
    for (int kk = 0; kk < 16; kk++){
      bf16x8 kb = *(const bf16x8*)(&Ks[cl][kk*16 + hi*8]);
      s = MFMA32(qa[kk], kb, s, 0, 0, 0);
    }

    // fixed-max softmax numerators (|logit| bounded ~1.7); lane's key = key0 + cl
    const bool valid = (key0 + cl) < PP;
    #pragma unroll
    for (int r = 0; r < 16; r++){
      float v = valid ? s[r]*SCALE : -1e30f;
      float p = __expf(v);
      den[r] += p;
      int qr = (r & 3) + 8*(r >> 2) + 4*hi;
      Ps[w][qr][cl] = (short)f2b(p);
    }
    // no barrier: wave w writes AND reads only Ps[w] (same-wave DS ops in-order;
    // validated on HW by R14/R15 refchecks)

    // O += P(32x32) @ V: A-frags from Ps, B-frags from Vs (V^T rows)
    bf16x8 pa0 = *(const bf16x8*)(&Ps[w][cl][hi*8]);
    bf16x8 pa1 = *(const bf16x8*)(&Ps[w][cl][16 + hi*8]);
    #pragma unroll
    for (int ct = 0; ct < 8; ct++){
      bf16x8 vb0 = *(const bf16x8*)(&Vs[ct*32 + cl][hi*8]);
      bf16x8 vb1 = *(const bf16x8*)(&Vs[ct*32 + cl][16 + hi*8]);
      o[ct] = MFMA32(pa0, vb0, o[ct], 0, 0, 0);
      o[ct] = MFMA32(pa1, vb1, o[ct], 0, 0, 0);
    }
    __syncthreads();   // protect Ks/Vs before next staging
  }

  // epilogue: reduce den across the 32 key-lanes, normalize, store
  #pragma unroll
  for (int r = 0; r < 16; r++){
    float dsum = den[r];
    #pragma unroll
    for (int off = 16; off >= 1; off >>= 1) dsum += __shfl_xor(dsum, off);
    float inv = 1.f/dsum;
    int srow = qbase + (r & 3) + 8*(r >> 2) + 4*hi;
    if (srow >= NN) continue;
    bool dg = (srow/PP == f);
    size_t x1base = ((size_t)(b*NN + srow)*FF + f)*CC;
    size_t xdbase = (size_t)(b*NN + srow)*CC;
    #pragma unroll
    for (int ct = 0; ct < 8; ct++){
      short val = (short)f2b(o[ct][r]*inv);
      x1[x1base + ct*32 + cl] = val;
      if (dg) xd[xdbase + ct*32 + cl] = val;
    }
  }
}

// ---------------- Stage-2 attention (unchanged — passed R12-R15) ----------------
__launch_bounds__(256)
__global__ void k16_attn2(const short* __restrict__ q2b, const short* __restrict__ k2v2,
                          float* __restrict__ attnp, short* __restrict__ x2)
{
  int idx = blockIdx.x*256 + threadIdx.x;
  if (idx >= MROWS*HH) return;
  const int h = idx & 7; const int row = idx >> 3;   // row = b*N + s

  float qv[32];
  {
    const short* qp = q2b + (size_t)row*CC + h*32;
    #pragma unroll
    for (int s4 = 0; s4 < 4; s4++){
      uint4 u = *(const uint4*)(qp + s4*8);
      const unsigned short* sp = (const unsigned short*)&u;
      #pragma unroll
      for (int j = 0; j < 8; j++) qv[s4*8 + j] = b2f(sp[j]);
    }
  }

  float lgt[FF];
  #pragma unroll
  for (int f = 0; f < FF; f++){
    const short* kp = k2v2 + ((size_t)row*FF + f)*512 + h*32;
    float a = 0.f;
    #pragma unroll
    for (int s4 = 0; s4 < 4; s4++){
      uint4 u = *(const uint4*)(kp + s4*8);
      const unsigned short* sp = (const unsigned short*)&u;
      #pragma unroll
      for (int j = 0; j < 8; j++) a += qv[s4*8 + j]*b2f(sp[j]);
    }
    lgt[f] = a;
  }

  float mx = lgt[0];
  #pragma unroll
  for (int f = 1; f < FF; f++) mx = fmaxf(mx, lgt[f]);
  float pr[FF], ps = 0.f;
  #pragma unroll
  for (int f = 0; f < FF; f++){ pr[f] = __expf(lgt[f] - mx); ps += pr[f]; }
  float inv = 1.f/ps;

  const int b = row / NN; const int s = row - b*NN;
  size_t ab = (((size_t)(b*HH + h))*NN + s)*FF;
  #pragma unroll
  for (int f = 0; f < FF; f++) attnp[ab + f] = pr[f]*inv;   // f32 store

  float xa[32] = {};
  #pragma unroll
  for (int f = 0; f < FF; f++){
    const short* vp = k2v2 + ((size_t)row*FF + f)*512 + 256 + h*32;
    float wgt = pr[f]*inv;
    #pragma unroll
    for (int s4 = 0; s4 < 4; s4++){
      uint4 u = *(const uint4*)(vp + s4*8);
      const unsigned short* sp = (const unsigned short*)&u;
      #pragma unroll
      for (int j = 0; j < 8; j++) xa[s4*8 + j] += wgt*b2f(sp[j]);
    }
  }
  #pragma unroll
  for (int s4 = 0; s4 < 4; s4++){
    unsigned short o[8];
    #pragma unroll
    for (int j = 0; j < 8; j++) o[j] = f2b(xa[s4*8 + j]);
    *(uint4*)(x2 + (size_t)row*CC + h*32 + s4*8) = *(uint4*)o;
  }
}

// ---------------- launcher ----------------
extern "C" void kernel_launch(void* const* d_in, const int* in_sizes, int n_in,
                              void* d_out, int out_size, void* d_ws, size_t ws_size,
                              hipStream_t stream)
{
  // bind inputs BY SIZE (validated rounds 10-15)
  int ix=-1, iwqkv=-1, iwpq=-1, iwpkv=-1, iwproj=-1, ib=-1;
  for (int i = 0; i < n_in; i++){
    switch (in_sizes[i]){
      case 4710400: ix = i; break;
      case 196608:  iwqkv = i; break;
      case 131072:  iwpkv = i; break;
      case 256:     ib = i; break;
      case 65536:   if (iwpq < 0) iwpq = i; else iwproj = i; break;
      default: break;
    }
  }
  if (ix < 0 || iwqkv < 0 || iwpq < 0 || iwpkv < 0 || iwproj < 0 || ib < 0){
    ix=0; iwqkv=1; iwpq=2; iwpkv=3; iwproj=4; ib=5;
  }
  const float* x     = (const float*)d_in[ix];
  const float* Wqkv  = (const float*)d_in[iwqkv];
  const float* Wpq   = (const float*)d_in[iwpq];
  const float* Wpkv  = (const float*)d_in[iwpkv];
  const float* Wproj = (const float*)d_in[iwproj];
  const float* bproj = (const float*)d_in[ib];

  char* ws = (char*)d_ws;
  if (ws_size < 208269312ULL) return;

  short* wq    = (short*)(ws + 0);               // 768*256
  short* wpq   = (short*)(ws + 393216);          // 256*256
  short* wpkv  = (short*)(ws + 524288);          // 512*256
  short* wprj  = (short*)(ws + 786432);          // 256*256
  short* xb    = (short*)(ws + 917504);          // 18400x256
  short* qkv   = (short*)(ws + 10338304);        // 18408x768 (8 slack rows zeroed)
  short* vt    = (short*)(ws + 38612992);        // 20x256x928
  short* x1    = (short*)(ws + 48115712);        // 92000x256
  short* xd    = (short*)(ws + 95219712);        // 18400x256
  short* k2v2  = (short*)(ws + 104640512);       // 92000x512
  short* q2b   = (short*)(ws + 198848512);       // 18400x256 -> end 208,269,312
  short* x2    = xb;                             // alias: xb dead after QKV GEMM

  float* outp  = (float*)d_out;                  // f32 out   [0 : 4,710,400)
  float* attnp = outp + 4710400;                 // f32 attn  [4,710,400 : 5,446,400)

  k16_cast<<<dim3(768), dim3(256), 0, stream>>>(Wqkv,  wq,   196608);
  k16_cast<<<dim3(256), dim3(256), 0, stream>>>(Wpq,   wpq,  65536);
  k16_cast<<<dim3(512), dim3(256), 0, stream>>>(Wpkv,  wpkv, 131072);
  k16_cast<<<dim3(256), dim3(256), 0, stream>>>(Wproj, wprj, 65536);
  k16_make_xb<<<dim3(4600), dim3(256), 0, stream>>>(x, xb);
  k16_zero<<<dim3(24), dim3(256), 0, stream>>>(qkv + (size_t)MROWS*768, 6144);

  // qkv = xb @ Wqkv^T           (MFMA)
  k16_gemm<0><<<dim3(144, 6), dim3(256), 0, stream>>>(xb, wq, qkv, nullptr, nullptr, MROWS, 256, 768, 1.0f);
  // V transpose for flash
  k16_vt<<<dim3(15, 4, 20), dim3(256), 0, stream>>>(qkv, vt);
  // stage-1 flash attention v5  (mfma 32x32x16, proper launch_bounds)
  k16_flash<<<dim3(36, 5, 4), dim3(256), 0, stream>>>(qkv, vt, x1, xd);
  // kv2 = x1 @ Wpkv^T           (MFMA)
  k16_gemm<0><<<dim3(719, 4), dim3(256), 0, stream>>>(x1, wpkv, k2v2, nullptr, nullptr, M2ROWS, 256, 512, 1.0f);
  // q2 = xd @ Wpq^T * scale     (MFMA)
  k16_gemm<0><<<dim3(144, 2), dim3(256), 0, stream>>>(xd, wpq, q2b, nullptr, nullptr, MROWS, 256, 256, SCALE);
  // stage-2 attention (f32 attn, bf16 x2)
  k16_attn2<<<dim3(575), dim3(256), 0, stream>>>(q2b, k2v2, attnp, x2);
  // out = x2 @ Wproj^T + bias   (MFMA, f32 permuted store)
  k16_gemm<1><<<dim3(144, 2), dim3(256), 0, stream>>>(x2, wprj, nullptr, outp, bproj, MROWS, 256, 256, 1.0f);
}